// Round 1
// baseline (317.446 us; speedup 1.0000x reference)
//
#include <hip/hip_runtime.h>
#include <math.h>

#define NLEV 10
#define TSZ 65536
#define P2 2654435761u
#define P3 805459861u

struct GS { float g[NLEV]; };

__global__ __launch_bounds__(256) void propmlp_kernel(
    const float* __restrict__ pos, const float* __restrict__ table,
    const float* __restrict__ W1, const float* __restrict__ b1,
    const float* __restrict__ W2, const float* __restrict__ b2,
    float* __restrict__ out, int N, GS gs)
{
    int i = blockIdx.x * blockDim.x + threadIdx.x;
    if (i >= N) return;

    float px = pos[i * 3 + 0];
    float py = pos[i * 3 + 1];
    float pz = pos[i * 3 + 2];

    float feats[2 * NLEV];

#pragma unroll
    for (int l = 0; l < NLEV; ++l) {
        float n = gs.g[l];
        float sx = px * n, sy = py * n, sz = pz * n;
        float fx = floorf(sx), fy = floorf(sy), fz = floorf(sz);
        float rx = sx - fx, ry = sy - fy, rz = sz - fz;
        unsigned bx = (unsigned)fx, by = (unsigned)fy, bz = (unsigned)fz;

        unsigned hx0 = bx,       hx1 = bx + 1u;
        unsigned hy0 = by * P2,  hy1 = hy0 + P2;
        unsigned hz0 = bz * P3,  hz1 = hz0 + P3;

        float wx1 = rx, wx0 = 1.f - rx;
        float wy1 = ry, wy0 = 1.f - ry;
        float wz1 = rz, wz0 = 1.f - rz;

        const float2* tl = (const float2*)table + (size_t)l * TSZ;

        float a0 = 0.f, a1 = 0.f;
#define CORNER(hx, hy, hz, wx, wy, wz)                         \
        {                                                      \
            unsigned idx = ((hx) ^ (hy) ^ (hz)) & (TSZ - 1);   \
            float2 f = tl[idx];                                \
            float w = (wx) * (wy) * (wz);                      \
            a0 = fmaf(f.x, w, a0);                             \
            a1 = fmaf(f.y, w, a1);                             \
        }
        CORNER(hx0, hy0, hz0, wx0, wy0, wz0)
        CORNER(hx0, hy0, hz1, wx0, wy0, wz1)
        CORNER(hx0, hy1, hz0, wx0, wy1, wz0)
        CORNER(hx0, hy1, hz1, wx0, wy1, wz1)
        CORNER(hx1, hy0, hz0, wx1, wy0, wz0)
        CORNER(hx1, hy0, hz1, wx1, wy0, wz1)
        CORNER(hx1, hy1, hz0, wx1, wy1, wz0)
        CORNER(hx1, hy1, hz1, wx1, wy1, wz1)
#undef CORNER
        feats[2 * l + 0] = a0;
        feats[2 * l + 1] = a1;
    }

    // MLP: relu(x @ W1 + b1) @ W2 + b2
    // W1/b1/W2/b2 accesses are wave-uniform -> scalar loads (constant cache),
    // vector pipe does pure FMAs. Two halves of 32 to cap VGPR pressure.
    float density = b2[0];
#pragma unroll
    for (int half = 0; half < 2; ++half) {
        float h[32];
#pragma unroll
        for (int j = 0; j < 32; ++j) h[j] = b1[half * 32 + j];
#pragma unroll
        for (int k = 0; k < 2 * NLEV; ++k) {
            float xk = feats[k];
            const float* w1row = W1 + k * 64 + half * 32;
#pragma unroll
            for (int j = 0; j < 32; ++j)
                h[j] = fmaf(xk, w1row[j], h[j]);
        }
#pragma unroll
        for (int j = 0; j < 32; ++j)
            density = fmaf(fmaxf(h[j], 0.f), W2[half * 32 + j], density);
    }

    out[i] = density;
}

extern "C" void kernel_launch(void* const* d_in, const int* in_sizes, int n_in,
                              void* d_out, int out_size, void* d_ws, size_t ws_size,
                              hipStream_t stream) {
    const float* pos   = (const float*)d_in[0];
    const float* table = (const float*)d_in[1];
    const float* W1    = (const float*)d_in[2];
    const float* b1    = (const float*)d_in[3];
    const float* W2    = (const float*)d_in[4];
    const float* b2    = (const float*)d_in[5];
    float* out = (float*)d_out;
    int N = in_sizes[0] / 3;

    // Grid sizes exactly as np.round(np.exp(np.linspace(log(16), log(512), 10)))
    // computed in double precision: {16,24,35,51,75,110,161,237,348,512}.
    GS gs;
    for (int l = 0; l < NLEV; ++l) {
        double t = log(16.0) + (log(512.0) - log(16.0)) * (double)l / 9.0;
        gs.g[l] = (float)round(exp(t));
    }

    int block = 256;
    int grid = (N + block - 1) / block;
    hipLaunchKernelGGL(propmlp_kernel, dim3(grid), dim3(block), 0, stream,
                       pos, table, W1, b1, W2, b2, out, N, gs);
}

// Round 2
// 317.374 us; speedup vs baseline: 1.0002x; 1.0002x over previous
//
#include <hip/hip_runtime.h>
#include <math.h>

#define NLEV 10
#define TSZ 65536
#define MASK (TSZ - 1)
#define P2 2654435761u
#define P3 805459861u

struct GS { float g[NLEV]; };

__device__ __forceinline__ void level_setup(
    float px, float py, float pz, float n,
    unsigned idx[8], float& rx, float& ry, float& rz)
{
    float sx = px * n, sy = py * n, sz = pz * n;
    float fx = floorf(sx), fy = floorf(sy), fz = floorf(sz);
    rx = sx - fx; ry = sy - fy; rz = sz - fz;
    unsigned bx = (unsigned)fx, by = (unsigned)fy, bz = (unsigned)fz;
    unsigned hx0 = bx,      hx1 = bx + 1u;
    unsigned hy0 = by * P2, hy1 = hy0 + P2;
    unsigned hz0 = bz * P3, hz1 = hz0 + P3;
    idx[0] = (hx0 ^ hy0 ^ hz0) & MASK;
    idx[1] = (hx0 ^ hy0 ^ hz1) & MASK;
    idx[2] = (hx0 ^ hy1 ^ hz0) & MASK;
    idx[3] = (hx0 ^ hy1 ^ hz1) & MASK;
    idx[4] = (hx1 ^ hy0 ^ hz0) & MASK;
    idx[5] = (hx1 ^ hy0 ^ hz1) & MASK;
    idx[6] = (hx1 ^ hy1 ^ hz0) & MASK;
    idx[7] = (hx1 ^ hy1 ^ hz1) & MASK;
}

__global__ __launch_bounds__(256) void propmlp_kernel(
    const float* __restrict__ pos, const float* __restrict__ table,
    const float* __restrict__ W1, const float* __restrict__ b1,
    const float* __restrict__ W2, const float* __restrict__ b2,
    float* __restrict__ out, int N, GS gs)
{
    int i = blockIdx.x * blockDim.x + threadIdx.x;
    if (i >= N) return;

    float px = pos[i * 3 + 0];
    float py = pos[i * 3 + 1];
    float pz = pos[i * 3 + 2];

    float feats[2 * NLEV];

    // Software-pipelined hash-grid encode: while level l's 8 gathers are
    // being consumed, level l+1's 8 gathers are already in flight.
    // fa/fb are explicit register double-buffers (~16 loads outstanding).
    const float2* tab2 = (const float2*)table;

    unsigned ia[8], ib[8];
    float rxa, rya, rza, rxb, ryb, rzb;
    float2 fa[8], fb[8];

    level_setup(px, py, pz, gs.g[0], ia, rxa, rya, rza);
#pragma unroll
    for (int c = 0; c < 8; ++c) fa[c] = tab2[ia[c]];

#pragma unroll
    for (int l = 0; l < NLEV; ++l) {
        // Issue next level's loads before consuming this level's.
        if (l + 1 < NLEV) {
            level_setup(px, py, pz, gs.g[l + 1], ib, rxb, ryb, rzb);
#pragma unroll
            for (int c = 0; c < 8; ++c) fb[c] = tab2[(size_t)(l + 1) * TSZ + ib[c]];
        }

        float wx1 = rxa, wx0 = 1.f - rxa;
        float wy1 = rya, wy0 = 1.f - rya;
        float wz1 = rza, wz0 = 1.f - rza;
        float w0 = wx0 * wy0 * wz0;
        float w1 = wx0 * wy0 * wz1;
        float w2 = wx0 * wy1 * wz0;
        float w3 = wx0 * wy1 * wz1;
        float w4 = wx1 * wy0 * wz0;
        float w5 = wx1 * wy0 * wz1;
        float w6 = wx1 * wy1 * wz0;
        float w7 = wx1 * wy1 * wz1;

        float a0, a1;
        a0 = fa[0].x * w0;           a1 = fa[0].y * w0;
        a0 = fmaf(fa[1].x, w1, a0);  a1 = fmaf(fa[1].y, w1, a1);
        a0 = fmaf(fa[2].x, w2, a0);  a1 = fmaf(fa[2].y, w2, a1);
        a0 = fmaf(fa[3].x, w3, a0);  a1 = fmaf(fa[3].y, w3, a1);
        a0 = fmaf(fa[4].x, w4, a0);  a1 = fmaf(fa[4].y, w4, a1);
        a0 = fmaf(fa[5].x, w5, a0);  a1 = fmaf(fa[5].y, w5, a1);
        a0 = fmaf(fa[6].x, w6, a0);  a1 = fmaf(fa[6].y, w6, a1);
        a0 = fmaf(fa[7].x, w7, a0);  a1 = fmaf(fa[7].y, w7, a1);
        feats[2 * l + 0] = a0;
        feats[2 * l + 1] = a1;

        // Rotate double-buffer (full unroll -> pure register renames).
        if (l + 1 < NLEV) {
#pragma unroll
            for (int c = 0; c < 8; ++c) fa[c] = fb[c];
            rxa = rxb; rya = ryb; rza = rzb;
        }
    }

    // MLP: relu(x @ W1 + b1) @ W2 + b2. Weights are wave-uniform ->
    // scalar-cache broadcasts; vector pipe does pure FMAs.
    float density = b2[0];
#pragma unroll
    for (int half = 0; half < 2; ++half) {
        float h[32];
#pragma unroll
        for (int j = 0; j < 32; ++j) h[j] = b1[half * 32 + j];
#pragma unroll
        for (int k = 0; k < 2 * NLEV; ++k) {
            float xk = feats[k];
            const float* w1row = W1 + k * 64 + half * 32;
#pragma unroll
            for (int j = 0; j < 32; ++j)
                h[j] = fmaf(xk, w1row[j], h[j]);
        }
#pragma unroll
        for (int j = 0; j < 32; ++j)
            density = fmaf(fmaxf(h[j], 0.f), W2[half * 32 + j], density);
    }

    out[i] = density;
}

extern "C" void kernel_launch(void* const* d_in, const int* in_sizes, int n_in,
                              void* d_out, int out_size, void* d_ws, size_t ws_size,
                              hipStream_t stream) {
    const float* pos   = (const float*)d_in[0];
    const float* table = (const float*)d_in[1];
    const float* W1    = (const float*)d_in[2];
    const float* b1    = (const float*)d_in[3];
    const float* W2    = (const float*)d_in[4];
    const float* b2    = (const float*)d_in[5];
    float* out = (float*)d_out;
    int N = in_sizes[0] / 3;

    // Grid sizes exactly as np.round(np.exp(np.linspace(log(16), log(512), 10)))
    // computed in double precision: {16,24,35,51,75,110,161,237,348,512}.
    GS gs;
    for (int l = 0; l < NLEV; ++l) {
        double t = log(16.0) + (log(512.0) - log(16.0)) * (double)l / 9.0;
        gs.g[l] = (float)round(exp(t));
    }

    int block = 256;
    int grid = (N + block - 1) / block;
    hipLaunchKernelGGL(propmlp_kernel, dim3(grid), dim3(block), 0, stream,
                       pos, table, W1, b1, W2, b2, out, N, gs);
}

// Round 3
// 246.068 us; speedup vs baseline: 1.2901x; 1.2898x over previous
//
#include <hip/hip_runtime.h>
#include <math.h>

#define NLEV 10
#define TSZ 65536
#define MASK (TSZ - 1)
#define P2 2654435761u
#define P3 805459861u
#define NBUCK 32768   // 32x32x32 Morton buckets

struct GS { float g[NLEV]; };

// ---------------- encode + MLP (shared body) ----------------

__device__ __forceinline__ float encode_mlp(
    float px, float py, float pz, const float* __restrict__ table,
    const float* __restrict__ W1, const float* __restrict__ b1,
    const float* __restrict__ W2, const float* __restrict__ b2, const GS& gs)
{
    float feats[2 * NLEV];
    const float2* tab2 = (const float2*)table;

#pragma unroll
    for (int l = 0; l < NLEV; ++l) {
        float n = gs.g[l];
        float sx = px * n, sy = py * n, sz = pz * n;
        float fx = floorf(sx), fy = floorf(sy), fz = floorf(sz);
        float rx = sx - fx, ry = sy - fy, rz = sz - fz;
        unsigned bx = (unsigned)fx, by = (unsigned)fy, bz = (unsigned)fz;

        unsigned hx0 = bx,      hx1 = bx + 1u;
        unsigned hy0 = by * P2, hy1 = hy0 + P2;
        unsigned hz0 = bz * P3, hz1 = hz0 + P3;

        float wx1 = rx, wx0 = 1.f - rx;
        float wy1 = ry, wy0 = 1.f - ry;
        float wz1 = rz, wz0 = 1.f - rz;

        const float2* tl = tab2 + (size_t)l * TSZ;
        float a0 = 0.f, a1 = 0.f;
#define CORNER(hx, hy, hz, wx, wy, wz)                         \
        {                                                      \
            unsigned idx = ((hx) ^ (hy) ^ (hz)) & MASK;        \
            float2 f = tl[idx];                                \
            float w = (wx) * (wy) * (wz);                      \
            a0 = fmaf(f.x, w, a0);                             \
            a1 = fmaf(f.y, w, a1);                             \
        }
        CORNER(hx0, hy0, hz0, wx0, wy0, wz0)
        CORNER(hx0, hy0, hz1, wx0, wy0, wz1)
        CORNER(hx0, hy1, hz0, wx0, wy1, wz0)
        CORNER(hx0, hy1, hz1, wx0, wy1, wz1)
        CORNER(hx1, hy0, hz0, wx1, wy0, wz0)
        CORNER(hx1, hy0, hz1, wx1, wy0, wz1)
        CORNER(hx1, hy1, hz0, wx1, wy1, wz0)
        CORNER(hx1, hy1, hz1, wx1, wy1, wz1)
#undef CORNER
        feats[2 * l + 0] = a0;
        feats[2 * l + 1] = a1;
    }

    float density = b2[0];
#pragma unroll
    for (int half = 0; half < 2; ++half) {
        float h[32];
#pragma unroll
        for (int j = 0; j < 32; ++j) h[j] = b1[half * 32 + j];
#pragma unroll
        for (int k = 0; k < 2 * NLEV; ++k) {
            float xk = feats[k];
            const float* w1row = W1 + k * 64 + half * 32;
#pragma unroll
            for (int j = 0; j < 32; ++j)
                h[j] = fmaf(xk, w1row[j], h[j]);
        }
#pragma unroll
        for (int j = 0; j < 32; ++j)
            density = fmaf(fmaxf(h[j], 0.f), W2[half * 32 + j], density);
    }
    return density;
}

// ---------------- sort pipeline ----------------

__device__ __forceinline__ unsigned part5(unsigned x) {
    // spread 5 bits so consecutive bits land every 3rd position
    unsigned r = (x & 1u);
    r |= (x & 2u) << 2;
    r |= (x & 4u) << 4;
    r |= (x & 8u) << 6;
    r |= (x & 16u) << 8;
    return r;
}

__global__ __launch_bounds__(256) void hist_kernel(
    const float* __restrict__ pos, unsigned* __restrict__ hist,
    unsigned* __restrict__ keys, int N)
{
    int i = blockIdx.x * blockDim.x + threadIdx.x;
    if (i >= N) return;
    float px = pos[i * 3 + 0], py = pos[i * 3 + 1], pz = pos[i * 3 + 2];
    unsigned cx = min(31u, (unsigned)(px * 32.f));
    unsigned cy = min(31u, (unsigned)(py * 32.f));
    unsigned cz = min(31u, (unsigned)(pz * 32.f));
    unsigned key = part5(cx) | (part5(cy) << 1) | (part5(cz) << 2);
    keys[i] = key;
    atomicAdd(&hist[key], 1u);
}

__global__ __launch_bounds__(1024) void scan_kernel(
    const unsigned* __restrict__ hist, unsigned* __restrict__ bases)
{
    __shared__ unsigned sums[1024];
    int t = threadIdx.x;
    unsigned local[32];
    unsigned s = 0;
#pragma unroll
    for (int k = 0; k < 32; ++k) { local[k] = hist[t * 32 + k]; s += local[k]; }
    sums[t] = s;
    __syncthreads();
    for (int off = 1; off < 1024; off <<= 1) {
        unsigned v = (t >= off) ? sums[t - off] : 0u;
        __syncthreads();
        sums[t] += v;
        __syncthreads();
    }
    unsigned base = (t > 0) ? sums[t - 1] : 0u;
#pragma unroll
    for (int k = 0; k < 32; ++k) { bases[t * 32 + k] = base; base += local[k]; }
}

__global__ __launch_bounds__(256) void scatter_kernel(
    const float* __restrict__ pos, const unsigned* __restrict__ keys,
    unsigned* __restrict__ bases, unsigned* __restrict__ idx_sorted,
    float* __restrict__ pos_sorted, int N)
{
    int i = blockIdx.x * blockDim.x + threadIdx.x;
    if (i >= N) return;
    unsigned k = keys[i];
    unsigned j = atomicAdd(&bases[k], 1u);
    idx_sorted[j] = (unsigned)i;
    pos_sorted[j * 3 + 0] = pos[i * 3 + 0];
    pos_sorted[j * 3 + 1] = pos[i * 3 + 1];
    pos_sorted[j * 3 + 2] = pos[i * 3 + 2];
}

__global__ __launch_bounds__(256) void compute_sorted_kernel(
    const float* __restrict__ pos_sorted, const unsigned* __restrict__ idx_sorted,
    const float* __restrict__ table,
    const float* __restrict__ W1, const float* __restrict__ b1,
    const float* __restrict__ W2, const float* __restrict__ b2,
    float* __restrict__ out, int N, GS gs)
{
    int i = blockIdx.x * blockDim.x + threadIdx.x;
    if (i >= N) return;
    float px = pos_sorted[i * 3 + 0];
    float py = pos_sorted[i * 3 + 1];
    float pz = pos_sorted[i * 3 + 2];
    float density = encode_mlp(px, py, pz, table, W1, b1, W2, b2, gs);
    out[idx_sorted[i]] = density;
}

__global__ __launch_bounds__(256) void compute_direct_kernel(
    const float* __restrict__ pos, const float* __restrict__ table,
    const float* __restrict__ W1, const float* __restrict__ b1,
    const float* __restrict__ W2, const float* __restrict__ b2,
    float* __restrict__ out, int N, GS gs)
{
    int i = blockIdx.x * blockDim.x + threadIdx.x;
    if (i >= N) return;
    float px = pos[i * 3 + 0], py = pos[i * 3 + 1], pz = pos[i * 3 + 2];
    out[i] = encode_mlp(px, py, pz, table, W1, b1, W2, b2, gs);
}

// ---------------- launch ----------------

extern "C" void kernel_launch(void* const* d_in, const int* in_sizes, int n_in,
                              void* d_out, int out_size, void* d_ws, size_t ws_size,
                              hipStream_t stream) {
    const float* pos   = (const float*)d_in[0];
    const float* table = (const float*)d_in[1];
    const float* W1    = (const float*)d_in[2];
    const float* b1    = (const float*)d_in[3];
    const float* W2    = (const float*)d_in[4];
    const float* b2    = (const float*)d_in[5];
    float* out = (float*)d_out;
    int N = in_sizes[0] / 3;

    // Grid sizes exactly np.round(np.exp(np.linspace(log16, log512, 10)))
    GS gs;
    for (int l = 0; l < NLEV; ++l) {
        double t = log(16.0) + (log(512.0) - log(16.0)) * (double)l / 9.0;
        gs.g[l] = (float)round(exp(t));
    }

    int block = 256;
    int grid = (N + block - 1) / block;

    // Workspace layout
    size_t off_hist = 0;                               // NBUCK u32
    size_t off_keys = off_hist + (size_t)NBUCK * 4;    // N u32
    size_t off_idx  = off_keys + (size_t)N * 4;        // N u32
    size_t off_pos  = off_idx + (size_t)N * 4;         // N*3 f32
    size_t need     = off_pos + (size_t)N * 12;

    if (ws_size < need) {
        hipLaunchKernelGGL(compute_direct_kernel, dim3(grid), dim3(block), 0, stream,
                           pos, table, W1, b1, W2, b2, out, N, gs);
        return;
    }

    char* ws = (char*)d_ws;
    unsigned* hist       = (unsigned*)(ws + off_hist);
    unsigned* keys       = (unsigned*)(ws + off_keys);
    unsigned* idx_sorted = (unsigned*)(ws + off_idx);
    float*    pos_sorted = (float*)   (ws + off_pos);

    // hist doubles as running bases after the scan; must re-zero every call.
    hipMemsetAsync(hist, 0, (size_t)NBUCK * 4, stream);
    hipLaunchKernelGGL(hist_kernel, dim3(grid), dim3(block), 0, stream,
                       pos, hist, keys, N);
    // scan writes bases back over hist (separate region not needed: write in place
    // would race; reuse keys? -> use a dedicated bases region = hist (in-place safe
    // because scan reads all before writing? it doesn't). Use hist as input and
    // write bases into a second small region carved before keys? Simplest: scan
    // into hist itself is unsafe; put bases right after hist inside the slack of
    // keys? Not available. So: bases overwrite hist via separate buffer:
    // we instead allocate bases inside 'keys' tail? No - keys fully used.
    // Use a second pass trick: scan_kernel reads hist into registers first
    // (single workgroup reads ALL its inputs before any write? Not guaranteed
    // across threads) -> keep it safe with a tiny dedicated region: carve 128KB
    // more; ws check above accounts need+128KB below.
    unsigned* bases = hist; // replaced below if slack available
    // (fallthrough handled at compile time: we reserved extra in 'need'? no)
    // Safe approach: scan into 'keys'?? occupied. -> Do scan with barrier:
    // scan_kernel loads all of hist in its first phase and __syncthreads()
    // before writing bases over the same memory. Single workgroup => barrier
    // makes in-place safe.
    hipLaunchKernelGGL(scan_kernel, dim3(1), dim3(1024), 0, stream, hist, bases);
    hipLaunchKernelGGL(scatter_kernel, dim3(grid), dim3(block), 0, stream,
                       pos, keys, bases, idx_sorted, pos_sorted, N);
    hipLaunchKernelGGL(compute_sorted_kernel, dim3(grid), dim3(block), 0, stream,
                       pos_sorted, idx_sorted, table, W1, b1, W2, b2, out, N, gs);
}